// Round 9
// baseline (2351.305 us; speedup 1.0000x reference)
//
#include <hip/hip_runtime.h>
#include <stdint.h>

#define NE    8
#define HID   2048
#define INTER 7168
#define TTOK  8192
#define NT1   (HID / 64)    // 32 K-tiles for pass1
#define NT2   (INTER / 64)  // 112 K-tiles for pass2

typedef __bf16 bf16;
typedef bf16 bf16x4 __attribute__((ext_vector_type(4)));
typedef bf16 bf16x8 __attribute__((ext_vector_type(8)));
typedef float f32x4 __attribute__((ext_vector_type(4)));

__device__ __forceinline__ void glds16(const void* g, void* l) {
  __builtin_amdgcn_global_load_lds((__attribute__((address_space(1))) void*)g,
                                   (__attribute__((address_space(3))) void*)l, 16, 0, 0);
}

// ---------------- fp32 -> bf16 conversion ----------------
__global__ void cvt_f32_bf16(const float* __restrict__ src, bf16* __restrict__ dst, long n) {
  long i = (long)blockIdx.x * blockDim.x + threadIdx.x;
  long stride = (long)gridDim.x * blockDim.x;
  for (long j = i * 4; j < n; j += stride * 4) {
    float4 v = *(const float4*)(src + j);
    bf16x4 o = {(bf16)v.x, (bf16)v.y, (bf16)v.z, (bf16)v.w};
    *(bf16x4*)(dst + j) = o;
  }
}

// ---------------- router ----------------
__global__ void router_kernel(const float* __restrict__ x, const float* __restrict__ gw,
                              int* __restrict__ topk_e, float* __restrict__ topk_w) {
  const int wid = threadIdx.x >> 6, lane = threadIdx.x & 63;
  const int t = blockIdx.x * 4 + wid;
  if (t >= TTOK) return;
  const float* xr = x + (size_t)t * HID;
  float xv[32];
#pragma unroll
  for (int i = 0; i < 32; ++i) xv[i] = xr[lane + 64 * i];
  float lg[NE];
#pragma unroll
  for (int e = 0; e < NE; ++e) {
    const float* g = gw + e * HID;
    float s = 0.f;
#pragma unroll
    for (int i = 0; i < 32; ++i) s += xv[i] * g[lane + 64 * i];
#pragma unroll
    for (int off = 32; off; off >>= 1) s += __shfl_down(s, off);
    lg[e] = s;
  }
  if (lane == 0) {
    int i1 = 0;
#pragma unroll
    for (int e = 1; e < NE; ++e) if (lg[e] > lg[i1]) i1 = e;
    int i2 = (i1 == 0) ? 1 : 0;
#pragma unroll
    for (int e = 0; e < NE; ++e) if (e != i2 && e != i1 && lg[e] > lg[i2]) i2 = e;
    float r = __expf(lg[i2] - lg[i1]);
    float wa = 1.f / (1.f + r);
    topk_e[2 * t] = i1; topk_e[2 * t + 1] = i2;
    topk_w[2 * t] = wa; topk_w[2 * t + 1] = 1.f - wa;
  }
}

__global__ void gather_kernel(const int* __restrict__ topk_e, const float* __restrict__ topk_w,
                              int* __restrict__ cnt, int* __restrict__ ltok, float* __restrict__ lw) {
  const int t = blockIdx.x * blockDim.x + threadIdx.x;
  if (t >= TTOK) return;
#pragma unroll
  for (int j = 0; j < 2; ++j) {
    int e = topk_e[2 * t + j];
    int s = atomicAdd(&cnt[e], 1);
    ltok[e * TTOK + s] = t;
    lw[e * TTOK + s] = topk_w[2 * t + j];
  }
}

__global__ void prefix_kernel(const int* __restrict__ cnt, int* __restrict__ base) {
  if (threadIdx.x == 0 && blockIdx.x == 0) {
    int b = 0;
    for (int e = 0; e < NE; ++e) { base[e] = b; b += cnt[e]; }
  }
}

// ============ 256x256 GEMM, 16x16x32 MFMA, balanced {4,8,4,8}-read phases ============
// LDS: 2 dbuf x (A,B) x 256 x 64 bf16 = 128 KiB. 8 waves (2M x 4N).
// Swizzle: 16B-slot ^= (row & 7) on glds global source AND ds_read addr.
// Phase order per K-tile (9 barriers):
//  ph1: read b0(4); stage B1(t+1)[other buf]; BAR; lgkm0; MFMA Q00(a0,b0); BAR
//  ph2: read a1(8); BAR; lgkm0; MFMA Q10(a1,b0); BAR
//  ph3: read b1(4); stage A0+A1(t+2) [A-readers drained ph2]; BAR; lgkm0; MFMA Q01(a0,b1); BAR
//  ph4: stage B0(t+2) [B-readers drained ph3]; MFMA Q11(a1,b1);
//       vmcnt(10) [all waves confirm A(t+1) landed: queue walk 14-outstanding keep-10];
//       BAR; early-read a0(t+1) x8 from next buf; vmcnt(6) [confirm B0/B1(t+1)]; BAR
// Cross-wave rule: LDS rows staged by other waves may only be ds_read after a barrier
// that follows every wave's vmcnt covering those stage loads (vmcnt is per-wave).
// Tail: t+2==NT -> pre vmcnt(4), post vmcnt(0); t+1==NT -> skip early-read, vmcnt(0).

#define MFMA(a, b, c) __builtin_amdgcn_mfma_f32_16x16x32_bf16((a), (b), (c), 0, 0, 0)

#define STAGE_A(h, kt) do { int _b = ((kt) & 1) * 32768; size_t _k = (size_t)(kt) * 128; \
    glds16(bA + oA[(h)*2 + 0] + _k, ldsA + _b + (h) * 16384 + d0); \
    glds16(bA + oA[(h)*2 + 1] + _k, ldsA + _b + (h) * 16384 + d1); } while (0)
#define STAGE_B(h, kt) do { int _b = ((kt) & 1) * 32768; size_t _k = (size_t)(kt) * 128; \
    glds16(bB + oB[(h)*2 + 0] + _k, ldsB + _b + (h) * 16384 + d0); \
    glds16(bB + oB[(h)*2 + 1] + _k, ldsB + _b + (h) * 16384 + d1); } while (0)

#define RD_AX(base, mf, ks) (*(const bf16x8*)(ldsA + (base) + arow + (mf) * (16 * 128) + ((ks) ? kcol1 : kcol0)))
#define RD_B(nf, ks) (*(const bf16x8*)(ldsB + curb + brow + (nf) * (16 * 128) + ((ks) ? kcol1 : kcol0)))

#define BAR()   __builtin_amdgcn_s_barrier()
#define LGKM0() do { asm volatile("s_waitcnt lgkmcnt(0)" ::: "memory"); \
                     __builtin_amdgcn_sched_barrier(0); } while (0)
#define SCHED0() __builtin_amdgcn_sched_barrier(0)

// ---------------- pass1: h = silu(x w1^T) * (x w3^T) ----------------
__launch_bounds__(512, 2)
__global__ void pass1_kernel(const bf16* __restrict__ xb, const bf16* __restrict__ w1b,
                             bf16* __restrict__ hbuf, const int* __restrict__ cnt,
                             const int* __restrict__ basep, const int* __restrict__ ltok) {
  const int e = blockIdx.z;
  const int c = cnt[e];
  const int tm = blockIdx.y;
  if (tm * 256 >= c) return;
  const int tn = blockIdx.x;

  __shared__ __align__(16) bf16 sA[2][256 * 64];
  __shared__ __align__(16) bf16 sB[2][256 * 64];
  char* const ldsA = (char*)&sA[0][0];
  char* const ldsB = (char*)&sB[0][0];

  const int tid = threadIdx.x;
  const int r0 = tid >> 3;
  const int ls = (tid & 7) ^ (r0 & 7);
  const int d0 = tid * 16, d1 = (tid + 512) * 16;
  const char* const bA = (const char*)xb;
  const char* const bB = (const char*)w1b;  // w3b contiguous after w1b

  uint32_t oA[4], oB[4];
#pragma unroll
  for (int i = 0; i < 4; ++i) {
    int trow = i * 64 + r0;
    int slot = tm * 256 + trow; if (slot >= c) slot = c - 1;
    oA[i] = (uint32_t)((size_t)ltok[e * TTOK + slot] * (HID * 2) + ls * 16);
    int br = i * 64 + r0;
    int w = (br >> 4) & 1;
    int wr = tn * 128 + ((br >> 5) << 4) + (br & 15);
    size_t off = ((size_t)e * INTER + wr) * (HID * 2) + (size_t)ls * 16;
    if (w) off += (size_t)NE * INTER * HID * 2;
    oB[i] = (uint32_t)off;
  }

  const int lane = tid & 63, wid = tid >> 6;
  const int wm = wid >> 2, wn = wid & 3;
  const int ln15 = lane & 15, kq = lane >> 4;
  const int swz = (ln15 & 7) << 4;
  const int kcol0 = (kq * 16) ^ swz;
  const int kcol1 = (64 + kq * 16) ^ swz;
  const int arow = (wm * 128 + ln15) * 128;
  const int brow = (wn * 64 + ln15) * 128;

  f32x4 acc[8][4];
#pragma unroll
  for (int m = 0; m < 8; ++m)
#pragma unroll
    for (int n = 0; n < 4; ++n) acc[m][n] = (f32x4){0.f, 0.f, 0.f, 0.f};

  // prologue: tile0 fully + A0,A1,B0 of tile1; confirm tile0; pre-read a0(tile0)
  STAGE_A(0, 0); STAGE_A(1, 0); STAGE_B(0, 0); STAGE_B(1, 0);
  asm volatile("s_waitcnt vmcnt(4)" ::: "memory");
  STAGE_A(0, 1); STAGE_A(1, 1); STAGE_B(0, 1);
  asm volatile("s_waitcnt vmcnt(6)" ::: "memory");
  BAR();

  bf16x8 a0[4][2], a1[4][2], b0[2][2], b1[2][2];
#pragma unroll
  for (int m = 0; m < 4; ++m) { a0[m][0] = RD_AX(0, m, 0); a0[m][1] = RD_AX(0, m, 1); }

  int cur = 0;
  for (int t = 0; t < NT1; ++t, cur ^= 1) {
    const int curb = cur * 32768;
    const int nxtb = (cur ^ 1) * 32768;
    // ---- phase 1 ----
#pragma unroll
    for (int n = 0; n < 2; ++n) { b0[n][0] = RD_B(n, 0); b0[n][1] = RD_B(n, 1); }
    if (t + 1 < NT1) STAGE_B(1, t + 1);
    BAR(); LGKM0();
    __builtin_amdgcn_s_setprio(1);
#pragma unroll
    for (int m = 0; m < 4; ++m)
#pragma unroll
      for (int n = 0; n < 2; ++n) {
        acc[m][n] = MFMA(a0[m][0], b0[n][0], acc[m][n]);
        acc[m][n] = MFMA(a0[m][1], b0[n][1], acc[m][n]);
      }
    __builtin_amdgcn_s_setprio(0);
    BAR();
    // ---- phase 2 ----
#pragma unroll
    for (int m = 0; m < 4; ++m) { a1[m][0] = RD_AX(curb, 4 + m, 0); a1[m][1] = RD_AX(curb, 4 + m, 1); }
    BAR(); LGKM0();
    __builtin_amdgcn_s_setprio(1);
#pragma unroll
    for (int m = 0; m < 4; ++m)
#pragma unroll
      for (int n = 0; n < 2; ++n) {
        acc[4 + m][n] = MFMA(a1[m][0], b0[n][0], acc[4 + m][n]);
        acc[4 + m][n] = MFMA(a1[m][1], b0[n][1], acc[4 + m][n]);
      }
    __builtin_amdgcn_s_setprio(0);
    BAR();
    // ---- phase 3 ----
#pragma unroll
    for (int n = 0; n < 2; ++n) { b1[n][0] = RD_B(2 + n, 0); b1[n][1] = RD_B(2 + n, 1); }
    if (t + 2 < NT1) { STAGE_A(0, t + 2); STAGE_A(1, t + 2); SCHED0(); }
    BAR(); LGKM0();
    __builtin_amdgcn_s_setprio(1);
#pragma unroll
    for (int m = 0; m < 4; ++m)
#pragma unroll
      for (int n = 0; n < 2; ++n) {
        acc[m][2 + n] = MFMA(a0[m][0], b1[n][0], acc[m][2 + n]);
        acc[m][2 + n] = MFMA(a0[m][1], b1[n][1], acc[m][2 + n]);
      }
    __builtin_amdgcn_s_setprio(0);
    BAR();
    // ---- phase 4 ----
    if (t + 2 < NT1) STAGE_B(0, t + 2);
    __builtin_amdgcn_s_setprio(1);
#pragma unroll
    for (int m = 0; m < 4; ++m)
#pragma unroll
      for (int n = 0; n < 2; ++n) {
        acc[4 + m][2 + n] = MFMA(a1[m][0], b1[n][0], acc[4 + m][2 + n]);
        acc[4 + m][2 + n] = MFMA(a1[m][1], b1[n][1], acc[4 + m][2 + n]);
      }
    __builtin_amdgcn_s_setprio(0);
    if (t + 1 < NT1) {
      if (t + 2 < NT1) asm volatile("s_waitcnt vmcnt(10)" ::: "memory");
      else             asm volatile("s_waitcnt vmcnt(4)"  ::: "memory");
      BAR();
#pragma unroll
      for (int m = 0; m < 4; ++m) { a0[m][0] = RD_AX(nxtb, m, 0); a0[m][1] = RD_AX(nxtb, m, 1); }
      if (t + 2 < NT1) asm volatile("s_waitcnt vmcnt(6)" ::: "memory");
      else             asm volatile("s_waitcnt vmcnt(0)" ::: "memory");
      BAR();
    } else {
      asm volatile("s_waitcnt vmcnt(0)" ::: "memory");
      BAR();
    }
  }

  // epilogue: silu(g)*u, thread-local pairs (nf0,nf1) and (nf2,nf3)
  const int be = basep[e];
#pragma unroll
  for (int mh = 0; mh < 2; ++mh)
#pragma unroll
    for (int mf = 0; mf < 4; ++mf)
#pragma unroll
      for (int j = 0; j < 4; ++j) {
        const int slot = tm * 256 + wm * 128 + mh * 64 + mf * 16 + kq * 4 + j;
        if (slot < c) {
          bf16* hrow = hbuf + (size_t)(be + slot) * INTER + tn * 128;
#pragma unroll
          for (int p = 0; p < 2; ++p) {
            const float g = acc[mh * 4 + mf][2 * p][j];
            const float u = acc[mh * 4 + mf][2 * p + 1][j];
            const float hv = g / (1.f + __expf(-g)) * u;
            hrow[wn * 32 + p * 16 + ln15] = (bf16)hv;
          }
        }
      }
}

// ---------------- pass2: out[t,:] += w * (h w2^T) ----------------
__launch_bounds__(512, 2)
__global__ void pass2_kernel(const bf16* __restrict__ hbuf, const bf16* __restrict__ w2b,
                             float* __restrict__ out, const int* __restrict__ cnt,
                             const int* __restrict__ basep, const int* __restrict__ ltok,
                             const float* __restrict__ lw) {
  const int e = blockIdx.z;
  const int c = cnt[e];
  const int tm = blockIdx.y;
  if (tm * 256 >= c) return;
  const int tn = blockIdx.x;

  __shared__ __align__(16) bf16 sA[2][256 * 64];
  __shared__ __align__(16) bf16 sB[2][256 * 64];
  char* const ldsA = (char*)&sA[0][0];
  char* const ldsB = (char*)&sB[0][0];

  const int tid = threadIdx.x;
  const int r0 = tid >> 3;
  const int ls = (tid & 7) ^ (r0 & 7);
  const int d0 = tid * 16, d1 = (tid + 512) * 16;
  const int be = basep[e];
  const char* const bA = (const char*)hbuf;
  const char* const bB = (const char*)w2b;

  uint32_t oA[4], oB[4];
#pragma unroll
  for (int i = 0; i < 4; ++i) {
    int trow = i * 64 + r0;
    int slot = tm * 256 + trow; if (slot >= c) slot = c - 1;
    oA[i] = (uint32_t)((size_t)(be + slot) * (INTER * 2) + ls * 16);
    oB[i] = (uint32_t)(((size_t)e * HID + tn * 256 + i * 64 + r0) * (INTER * 2) + (size_t)ls * 16);
  }

  const int lane = tid & 63, wid = tid >> 6;
  const int wm = wid >> 2, wn = wid & 3;
  const int ln15 = lane & 15, kq = lane >> 4;
  const int swz = (ln15 & 7) << 4;
  const int kcol0 = (kq * 16) ^ swz;
  const int kcol1 = (64 + kq * 16) ^ swz;
  const int arow = (wm * 128 + ln15) * 128;
  const int brow = (wn * 64 + ln15) * 128;

  f32x4 acc[8][4];
#pragma unroll
  for (int m = 0; m < 8; ++m)
#pragma unroll
    for (int n = 0; n < 4; ++n) acc[m][n] = (f32x4){0.f, 0.f, 0.f, 0.f};

  STAGE_A(0, 0); STAGE_A(1, 0); STAGE_B(0, 0); STAGE_B(1, 0);
  asm volatile("s_waitcnt vmcnt(4)" ::: "memory");
  STAGE_A(0, 1); STAGE_A(1, 1); STAGE_B(0, 1);
  asm volatile("s_waitcnt vmcnt(6)" ::: "memory");
  BAR();

  bf16x8 a0[4][2], a1[4][2], b0[2][2], b1[2][2];
#pragma unroll
  for (int m = 0; m < 4; ++m) { a0[m][0] = RD_AX(0, m, 0); a0[m][1] = RD_AX(0, m, 1); }

  int cur = 0;
  for (int t = 0; t < NT2; ++t, cur ^= 1) {
    const int curb = cur * 32768;
    const int nxtb = (cur ^ 1) * 32768;
    // ---- phase 1 ----
#pragma unroll
    for (int n = 0; n < 2; ++n) { b0[n][0] = RD_B(n, 0); b0[n][1] = RD_B(n, 1); }
    if (t + 1 < NT2) STAGE_B(1, t + 1);
    BAR(); LGKM0();
    __builtin_amdgcn_s_setprio(1);
#pragma unroll
    for (int m = 0; m < 4; ++m)
#pragma unroll
      for (int n = 0; n < 2; ++n) {
        acc[m][n] = MFMA(a0[m][0], b0[n][0], acc[m][n]);
        acc[m][n] = MFMA(a0[m][1], b0[n][1], acc[m][n]);
      }
    __builtin_amdgcn_s_setprio(0);
    BAR();
    // ---- phase 2 ----
#pragma unroll
    for (int m = 0; m < 4; ++m) { a1[m][0] = RD_AX(curb, 4 + m, 0); a1[m][1] = RD_AX(curb, 4 + m, 1); }
    BAR(); LGKM0();
    __builtin_amdgcn_s_setprio(1);
#pragma unroll
    for (int m = 0; m < 4; ++m)
#pragma unroll
      for (int n = 0; n < 2; ++n) {
        acc[4 + m][n] = MFMA(a1[m][0], b0[n][0], acc[4 + m][n]);
        acc[4 + m][n] = MFMA(a1[m][1], b0[n][1], acc[4 + m][n]);
      }
    __builtin_amdgcn_s_setprio(0);
    BAR();
    // ---- phase 3 ----
#pragma unroll
    for (int n = 0; n < 2; ++n) { b1[n][0] = RD_B(2 + n, 0); b1[n][1] = RD_B(2 + n, 1); }
    if (t + 2 < NT2) { STAGE_A(0, t + 2); STAGE_A(1, t + 2); SCHED0(); }
    BAR(); LGKM0();
    __builtin_amdgcn_s_setprio(1);
#pragma unroll
    for (int m = 0; m < 4; ++m)
#pragma unroll
      for (int n = 0; n < 2; ++n) {
        acc[m][2 + n] = MFMA(a0[m][0], b1[n][0], acc[m][2 + n]);
        acc[m][2 + n] = MFMA(a0[m][1], b1[n][1], acc[m][2 + n]);
      }
    __builtin_amdgcn_s_setprio(0);
    BAR();
    // ---- phase 4 ----
    if (t + 2 < NT2) STAGE_B(0, t + 2);
    __builtin_amdgcn_s_setprio(1);
#pragma unroll
    for (int m = 0; m < 4; ++m)
#pragma unroll
      for (int n = 0; n < 2; ++n) {
        acc[4 + m][2 + n] = MFMA(a1[m][0], b1[n][0], acc[4 + m][2 + n]);
        acc[4 + m][2 + n] = MFMA(a1[m][1], b1[n][1], acc[4 + m][2 + n]);
      }
    __builtin_amdgcn_s_setprio(0);
    if (t + 1 < NT2) {
      if (t + 2 < NT2) asm volatile("s_waitcnt vmcnt(10)" ::: "memory");
      else             asm volatile("s_waitcnt vmcnt(4)"  ::: "memory");
      BAR();
#pragma unroll
      for (int m = 0; m < 4; ++m) { a0[m][0] = RD_AX(nxtb, m, 0); a0[m][1] = RD_AX(nxtb, m, 1); }
      if (t + 2 < NT2) asm volatile("s_waitcnt vmcnt(6)" ::: "memory");
      else             asm volatile("s_waitcnt vmcnt(0)" ::: "memory");
      BAR();
    } else {
      asm volatile("s_waitcnt vmcnt(0)" ::: "memory");
      BAR();
    }
  }

#pragma unroll
  for (int mh = 0; mh < 2; ++mh)
#pragma unroll
    for (int mf = 0; mf < 4; ++mf)
#pragma unroll
      for (int j = 0; j < 4; ++j) {
        const int slot = tm * 256 + wm * 128 + mh * 64 + mf * 16 + kq * 4 + j;
        if (slot < c) {
          const int tok = ltok[e * TTOK + slot];
          const float wt = lw[e * TTOK + slot];
          float* orow = out + (size_t)tok * HID + tn * 256;
#pragma unroll
          for (int n = 0; n < 4; ++n)
            atomicAdd(orow + wn * 64 + n * 16 + ln15, wt * acc[mh * 4 + mf][n][j]);
        }
      }
}

extern "C" void kernel_launch(void* const* d_in, const int* in_sizes, int n_in,
                              void* d_out, int out_size, void* d_ws, size_t ws_size,
                              hipStream_t stream) {
  const float* x  = (const float*)d_in[0];
  const float* gw = (const float*)d_in[1];
  const float* w1 = (const float*)d_in[2];
  const float* w3 = (const float*)d_in[3];
  const float* w2 = (const float*)d_in[4];
  float* out = (float*)d_out;

  char* ws = (char*)d_ws;
  size_t off = 0;
  auto take = [&](size_t bytes) -> char* {
    char* p = ws + off;
    off += (bytes + 255) & ~(size_t)255;
    return p;
  };
  bf16* xb    = (bf16*)take((size_t)TTOK * HID * 2);
  bf16* w1b   = (bf16*)take((size_t)NE * INTER * HID * 2);   // w3b MUST follow contiguously
  bf16* w3b   = (bf16*)take((size_t)NE * INTER * HID * 2);
  bf16* w2b   = (bf16*)take((size_t)NE * HID * INTER * 2);
  bf16* hbuf  = (bf16*)take((size_t)TTOK * 2 * INTER * 2);
  int*   topk_e = (int*)take(TTOK * 2 * 4);
  float* topk_w = (float*)take(TTOK * 2 * 4);
  int*   ltok   = (int*)take(NE * TTOK * 4);
  float* lwgt   = (float*)take(NE * TTOK * 4);
  int*   cntp   = (int*)take(64);
  int*   basep  = (int*)take(64);
  if (off > ws_size) return;

  hipMemsetAsync(d_out, 0, (size_t)out_size * 4, stream);
  hipMemsetAsync(cntp, 0, 64, stream);

  cvt_f32_bf16<<<2048, 256, 0, stream>>>(x,  xb,  (long)TTOK * HID);
  cvt_f32_bf16<<<4096, 256, 0, stream>>>(w1, w1b, (long)NE * INTER * HID);
  cvt_f32_bf16<<<4096, 256, 0, stream>>>(w3, w3b, (long)NE * INTER * HID);
  cvt_f32_bf16<<<4096, 256, 0, stream>>>(w2, w2b, (long)NE * HID * INTER);

  router_kernel<<<TTOK / 4, 256, 0, stream>>>(x, gw, topk_e, topk_w);
  gather_kernel<<<TTOK / 256, 256, 0, stream>>>(topk_e, topk_w, cntp, ltok, lwgt);
  prefix_kernel<<<1, 64, 0, stream>>>(cntp, basep);

  pass1_kernel<<<dim3(INTER / 128, TTOK / 256, NE), 512, 0, stream>>>(
      xb, w1b, hbuf, cntp, basep, ltok);
  pass2_kernel<<<dim3(HID / 256, TTOK / 256, NE), 512, 0, stream>>>(
      hbuf, w2b, out, cntp, basep, ltok, lwgt);
}

// Round 10
// 2311.936 us; speedup vs baseline: 1.0170x; 1.0170x over previous
//
#include <hip/hip_runtime.h>
#include <stdint.h>

#define NE    8
#define HID   2048
#define INTER 7168
#define TTOK  8192
#define NT1   (HID / 64)    // 32 K-tiles for pass1
#define NT2   (INTER / 64)  // 112 K-tiles for pass2

typedef __bf16 bf16;
typedef bf16 bf16x4 __attribute__((ext_vector_type(4)));
typedef bf16 bf16x8 __attribute__((ext_vector_type(8)));
typedef float f32x4 __attribute__((ext_vector_type(4)));

__device__ __forceinline__ void glds16(const void* g, void* l) {
  __builtin_amdgcn_global_load_lds((__attribute__((address_space(1))) void*)g,
                                   (__attribute__((address_space(3))) void*)l, 16, 0, 0);
}

// ---------------- fp32 -> bf16 conversion ----------------
__global__ void cvt_f32_bf16(const float* __restrict__ src, bf16* __restrict__ dst, long n) {
  long i = (long)blockIdx.x * blockDim.x + threadIdx.x;
  long stride = (long)gridDim.x * blockDim.x;
  for (long j = i * 4; j < n; j += stride * 4) {
    float4 v = *(const float4*)(src + j);
    bf16x4 o = {(bf16)v.x, (bf16)v.y, (bf16)v.z, (bf16)v.w};
    *(bf16x4*)(dst + j) = o;
  }
}

// ---------------- router ----------------
__global__ void router_kernel(const float* __restrict__ x, const float* __restrict__ gw,
                              int* __restrict__ topk_e, float* __restrict__ topk_w) {
  const int wid = threadIdx.x >> 6, lane = threadIdx.x & 63;
  const int t = blockIdx.x * 4 + wid;
  if (t >= TTOK) return;
  const float* xr = x + (size_t)t * HID;
  float xv[32];
#pragma unroll
  for (int i = 0; i < 32; ++i) xv[i] = xr[lane + 64 * i];
  float lg[NE];
#pragma unroll
  for (int e = 0; e < NE; ++e) {
    const float* g = gw + e * HID;
    float s = 0.f;
#pragma unroll
    for (int i = 0; i < 32; ++i) s += xv[i] * g[lane + 64 * i];
#pragma unroll
    for (int off = 32; off; off >>= 1) s += __shfl_down(s, off);
    lg[e] = s;
  }
  if (lane == 0) {
    int i1 = 0;
#pragma unroll
    for (int e = 1; e < NE; ++e) if (lg[e] > lg[i1]) i1 = e;
    int i2 = (i1 == 0) ? 1 : 0;
#pragma unroll
    for (int e = 0; e < NE; ++e) if (e != i2 && e != i1 && lg[e] > lg[i2]) i2 = e;
    float r = __expf(lg[i2] - lg[i1]);
    float wa = 1.f / (1.f + r);
    topk_e[2 * t] = i1; topk_e[2 * t + 1] = i2;
    topk_w[2 * t] = wa; topk_w[2 * t + 1] = 1.f - wa;
  }
}

// ---------------- stable sorted gather: one block per expert ----------------
// Deterministic and token-ascending: ltok[e*TTOK + k] lists tokens routed to e
// in increasing token order. Sequential-ish A-row gathers (L2-friendly) and
// token-ordered output atomics in pass2. Also writes cnt[e].
__global__ void gather_sorted(const int* __restrict__ topk_e, const float* __restrict__ topk_w,
                              int* __restrict__ cnt, int* __restrict__ ltok, float* __restrict__ lw) {
  const int e = blockIdx.x;      // 0..7
  const int tid = threadIdx.x;   // 0..255
  __shared__ int scan[256];
  __shared__ int basesh;
  if (tid == 0) basesh = 0;
  __syncthreads();
  for (int c0 = 0; c0 < TTOK; c0 += 256) {
    const int t = c0 + tid;
    const int e0 = topk_e[2 * t], e1 = topk_e[2 * t + 1];
    const int flag = (e0 == e) || (e1 == e);
    const float w = (e0 == e) ? topk_w[2 * t] : topk_w[2 * t + 1];
    scan[tid] = flag;
    __syncthreads();
    for (int off = 1; off < 256; off <<= 1) {
      int add = (tid >= off) ? scan[tid - off] : 0;
      __syncthreads();
      scan[tid] += add;
      __syncthreads();
    }
    const int rank = scan[tid] - flag;   // exclusive prefix
    const int total = scan[255];
    const int base = basesh;
    if (flag) { ltok[e * TTOK + base + rank] = t; lw[e * TTOK + base + rank] = w; }
    __syncthreads();
    if (tid == 0) basesh = base + total;
    __syncthreads();
  }
  if (tid == 0) cnt[e] = basesh;
}

__global__ void prefix_kernel(const int* __restrict__ cnt, int* __restrict__ base) {
  if (threadIdx.x == 0 && blockIdx.x == 0) {
    int b = 0;
    for (int e = 0; e < NE; ++e) { base[e] = b; b += cnt[e]; }
  }
}

// ============ 256x256 8-phase GEMM (round-6 schedule, best measured) ============
// LDS: 2 dbuf x (A,B) x 256 x 64 bf16 = 128 KiB. 8 waves (2M x 4N), 16x16x32 MFMA.
// Swizzle: 16B-slot ^= (row & 7) on glds global source AND ds_read addr.
// Stage slots (race-audited): ph1: B1(t+1) [other buf]; ph3: A0+A1(t+2) [A readers
// drained at ph2 lgkm0 + barrier]; ph4: B0(t+2) [B readers drained ph3]. vmcnt(6)
// at ph4 keeps exactly t+2's three half-tiles in flight.

#define MFMA(a, b, c) __builtin_amdgcn_mfma_f32_16x16x32_bf16((a), (b), (c), 0, 0, 0)

#define STAGE_A(h, kt) do { int _b = ((kt) & 1) * 32768; size_t _k = (size_t)(kt) * 128; \
    glds16(bA + oA[(h)*2 + 0] + _k, ldsA + _b + (h) * 16384 + d0); \
    glds16(bA + oA[(h)*2 + 1] + _k, ldsA + _b + (h) * 16384 + d1); } while (0)
#define STAGE_B(h, kt) do { int _b = ((kt) & 1) * 32768; size_t _k = (size_t)(kt) * 128; \
    glds16(bB + oB[(h)*2 + 0] + _k, ldsB + _b + (h) * 16384 + d0); \
    glds16(bB + oB[(h)*2 + 1] + _k, ldsB + _b + (h) * 16384 + d1); } while (0)

#define RD_A(mf, ks) (*(const bf16x8*)(ldsA + curb + arow + (mf) * (16 * 128) + ((ks) ? kcol1 : kcol0)))
#define RD_B(nf, ks) (*(const bf16x8*)(ldsB + curb + brow + (nf) * (16 * 128) + ((ks) ? kcol1 : kcol0)))

#define BAR()   __builtin_amdgcn_s_barrier()
#define LGKM0() do { asm volatile("s_waitcnt lgkmcnt(0)" ::: "memory"); \
                     __builtin_amdgcn_sched_barrier(0); } while (0)
#define SCHED0() __builtin_amdgcn_sched_barrier(0)

// ---------------- pass1: h = silu(x w1^T) * (x w3^T) ----------------
__launch_bounds__(512, 2)
__global__ void pass1_kernel(const bf16* __restrict__ xb, const bf16* __restrict__ w1b,
                             bf16* __restrict__ hbuf, const int* __restrict__ cnt,
                             const int* __restrict__ basep, const int* __restrict__ ltok) {
  const int e = blockIdx.z;
  const int c = cnt[e];
  const int tm = blockIdx.y;
  if (tm * 256 >= c) return;
  const int tn = blockIdx.x;

  __shared__ __align__(16) bf16 sA[2][256 * 64];
  __shared__ __align__(16) bf16 sB[2][256 * 64];
  char* const ldsA = (char*)&sA[0][0];
  char* const ldsB = (char*)&sB[0][0];

  const int tid = threadIdx.x;
  const int r0 = tid >> 3;
  const int ls = (tid & 7) ^ (r0 & 7);
  const int d0 = tid * 16, d1 = (tid + 512) * 16;
  const char* const bA = (const char*)xb;
  const char* const bB = (const char*)w1b;  // w3b contiguous after w1b

  uint32_t oA[4], oB[4];
#pragma unroll
  for (int i = 0; i < 4; ++i) {
    int trow = i * 64 + r0;
    int slot = tm * 256 + trow; if (slot >= c) slot = c - 1;
    oA[i] = (uint32_t)((size_t)ltok[e * TTOK + slot] * (HID * 2) + ls * 16);
    int br = i * 64 + r0;
    int w = (br >> 4) & 1;
    int wr = tn * 128 + ((br >> 5) << 4) + (br & 15);
    size_t off = ((size_t)e * INTER + wr) * (HID * 2) + (size_t)ls * 16;
    if (w) off += (size_t)NE * INTER * HID * 2;
    oB[i] = (uint32_t)off;
  }

  const int lane = tid & 63, wid = tid >> 6;
  const int wm = wid >> 2, wn = wid & 3;
  const int ln15 = lane & 15, kq = lane >> 4;
  const int swz = (ln15 & 7) << 4;
  const int kcol0 = (kq * 16) ^ swz;
  const int kcol1 = (64 + kq * 16) ^ swz;
  const int arow = (wm * 128 + ln15) * 128;
  const int brow = (wn * 64 + ln15) * 128;

  f32x4 acc[8][4];
#pragma unroll
  for (int m = 0; m < 8; ++m)
#pragma unroll
    for (int n = 0; n < 4; ++n) acc[m][n] = (f32x4){0.f, 0.f, 0.f, 0.f};

  STAGE_A(0, 0); STAGE_A(1, 0); STAGE_B(0, 0); STAGE_B(1, 0);
  asm volatile("s_waitcnt vmcnt(4)" ::: "memory");
  STAGE_A(0, 1); STAGE_A(1, 1); STAGE_B(0, 1);
  asm volatile("s_waitcnt vmcnt(6)" ::: "memory");
  BAR();

  bf16x8 a0[4][2], a1[4][2], b0[2][2], b1[2][2];
  int cur = 0;
  for (int t = 0; t < NT1; ++t, cur ^= 1) {
    const int curb = cur * 32768;
    // ---- phase 1: read a0(8)+b0(4), stage B1(t+1) [other buf], MFMA Q00 ----
#pragma unroll
    for (int m = 0; m < 4; ++m) { a0[m][0] = RD_A(m, 0); a0[m][1] = RD_A(m, 1); }
#pragma unroll
    for (int n = 0; n < 2; ++n) { b0[n][0] = RD_B(n, 0); b0[n][1] = RD_B(n, 1); }
    if (t + 1 < NT1) STAGE_B(1, t + 1);
    BAR(); LGKM0();
    __builtin_amdgcn_s_setprio(1);
#pragma unroll
    for (int m = 0; m < 4; ++m)
#pragma unroll
      for (int n = 0; n < 2; ++n) {
        acc[m][n] = MFMA(a0[m][0], b0[n][0], acc[m][n]);
        acc[m][n] = MFMA(a0[m][1], b0[n][1], acc[m][n]);
      }
    __builtin_amdgcn_s_setprio(0);
    BAR();
    // ---- phase 2: read a1(8), NO stage (A readers active), MFMA Q10 ----
#pragma unroll
    for (int m = 0; m < 4; ++m) { a1[m][0] = RD_A(4 + m, 0); a1[m][1] = RD_A(4 + m, 1); }
    BAR(); LGKM0();
    __builtin_amdgcn_s_setprio(1);
#pragma unroll
    for (int m = 0; m < 4; ++m)
#pragma unroll
      for (int n = 0; n < 2; ++n) {
        acc[4 + m][n] = MFMA(a1[m][0], b0[n][0], acc[4 + m][n]);
        acc[4 + m][n] = MFMA(a1[m][1], b0[n][1], acc[4 + m][n]);
      }
    __builtin_amdgcn_s_setprio(0);
    BAR();
    // ---- phase 3: read b1(4), stage A0+A1(t+2) [A drained ph2], MFMA Q01 ----
#pragma unroll
    for (int n = 0; n < 2; ++n) { b1[n][0] = RD_B(2 + n, 0); b1[n][1] = RD_B(2 + n, 1); }
    if (t + 2 < NT1) { STAGE_A(0, t + 2); STAGE_A(1, t + 2); SCHED0(); }
    BAR(); LGKM0();
    __builtin_amdgcn_s_setprio(1);
#pragma unroll
    for (int m = 0; m < 4; ++m)
#pragma unroll
      for (int n = 0; n < 2; ++n) {
        acc[m][2 + n] = MFMA(a0[m][0], b1[n][0], acc[m][2 + n]);
        acc[m][2 + n] = MFMA(a0[m][1], b1[n][1], acc[m][2 + n]);
      }
    __builtin_amdgcn_s_setprio(0);
    BAR();
    // ---- phase 4: stage B0(t+2) [B drained ph3], MFMA Q11, counted vmcnt ----
    if (t + 2 < NT1) STAGE_B(0, t + 2);
    __builtin_amdgcn_s_setprio(1);
#pragma unroll
    for (int m = 0; m < 4; ++m)
#pragma unroll
      for (int n = 0; n < 2; ++n) {
        acc[4 + m][2 + n] = MFMA(a1[m][0], b1[n][0], acc[4 + m][2 + n]);
        acc[4 + m][2 + n] = MFMA(a1[m][1], b1[n][1], acc[4 + m][2 + n]);
      }
    __builtin_amdgcn_s_setprio(0);
    if (t + 2 < NT1) asm volatile("s_waitcnt vmcnt(6)" ::: "memory");
    else             asm volatile("s_waitcnt vmcnt(0)" ::: "memory");
    BAR();
  }

  // epilogue: silu(g)*u, thread-local pairs (nf0,nf1) and (nf2,nf3)
  const int be = basep[e];
#pragma unroll
  for (int mh = 0; mh < 2; ++mh)
#pragma unroll
    for (int mf = 0; mf < 4; ++mf)
#pragma unroll
      for (int j = 0; j < 4; ++j) {
        const int slot = tm * 256 + wm * 128 + mh * 64 + mf * 16 + kq * 4 + j;
        if (slot < c) {
          bf16* hrow = hbuf + (size_t)(be + slot) * INTER + tn * 128;
#pragma unroll
          for (int p = 0; p < 2; ++p) {
            const float g = acc[mh * 4 + mf][2 * p][j];
            const float u = acc[mh * 4 + mf][2 * p + 1][j];
            const float hv = g / (1.f + __expf(-g)) * u;
            hrow[wn * 32 + p * 16 + ln15] = (bf16)hv;
          }
        }
      }
}

// ---------------- pass2: out[t,:] += w * (h w2^T) ----------------
__launch_bounds__(512, 2)
__global__ void pass2_kernel(const bf16* __restrict__ hbuf, const bf16* __restrict__ w2b,
                             float* __restrict__ out, const int* __restrict__ cnt,
                             const int* __restrict__ basep, const int* __restrict__ ltok,
                             const float* __restrict__ lw) {
  const int e = blockIdx.z;
  const int c = cnt[e];
  const int tm = blockIdx.y;
  if (tm * 256 >= c) return;
  const int tn = blockIdx.x;

  __shared__ __align__(16) bf16 sA[2][256 * 64];
  __shared__ __align__(16) bf16 sB[2][256 * 64];
  char* const ldsA = (char*)&sA[0][0];
  char* const ldsB = (char*)&sB[0][0];

  const int tid = threadIdx.x;
  const int r0 = tid >> 3;
  const int ls = (tid & 7) ^ (r0 & 7);
  const int d0 = tid * 16, d1 = (tid + 512) * 16;
  const int be = basep[e];
  const char* const bA = (const char*)hbuf;
  const char* const bB = (const char*)w2b;

  uint32_t oA[4], oB[4];
#pragma unroll
  for (int i = 0; i < 4; ++i) {
    int trow = i * 64 + r0;
    int slot = tm * 256 + trow; if (slot >= c) slot = c - 1;
    oA[i] = (uint32_t)((size_t)(be + slot) * (INTER * 2) + ls * 16);
    oB[i] = (uint32_t)(((size_t)e * HID + tn * 256 + i * 64 + r0) * (INTER * 2) + (size_t)ls * 16);
  }

  const int lane = tid & 63, wid = tid >> 6;
  const int wm = wid >> 2, wn = wid & 3;
  const int ln15 = lane & 15, kq = lane >> 4;
  const int swz = (ln15 & 7) << 4;
  const int kcol0 = (kq * 16) ^ swz;
  const int kcol1 = (64 + kq * 16) ^ swz;
  const int arow = (wm * 128 + ln15) * 128;
  const int brow = (wn * 64 + ln15) * 128;

  f32x4 acc[8][4];
#pragma unroll
  for (int m = 0; m < 8; ++m)
#pragma unroll
    for (int n = 0; n < 4; ++n) acc[m][n] = (f32x4){0.f, 0.f, 0.f, 0.f};

  STAGE_A(0, 0); STAGE_A(1, 0); STAGE_B(0, 0); STAGE_B(1, 0);
  asm volatile("s_waitcnt vmcnt(4)" ::: "memory");
  STAGE_A(0, 1); STAGE_A(1, 1); STAGE_B(0, 1);
  asm volatile("s_waitcnt vmcnt(6)" ::: "memory");
  BAR();

  bf16x8 a0[4][2], a1[4][2], b0[2][2], b1[2][2];
  int cur = 0;
  for (int t = 0; t < NT2; ++t, cur ^= 1) {
    const int curb = cur * 32768;
    // ---- phase 1 ----
#pragma unroll
    for (int m = 0; m < 4; ++m) { a0[m][0] = RD_A(m, 0); a0[m][1] = RD_A(m, 1); }
#pragma unroll
    for (int n = 0; n < 2; ++n) { b0[n][0] = RD_B(n, 0); b0[n][1] = RD_B(n, 1); }
    if (t + 1 < NT2) STAGE_B(1, t + 1);
    BAR(); LGKM0();
    __builtin_amdgcn_s_setprio(1);
#pragma unroll
    for (int m = 0; m < 4; ++m)
#pragma unroll
      for (int n = 0; n < 2; ++n) {
        acc[m][n] = MFMA(a0[m][0], b0[n][0], acc[m][n]);
        acc[m][n] = MFMA(a0[m][1], b0[n][1], acc[m][n]);
      }
    __builtin_amdgcn_s_setprio(0);
    BAR();
    // ---- phase 2 (no stage) ----
#pragma unroll
    for (int m = 0; m < 4; ++m) { a1[m][0] = RD_A(4 + m, 0); a1[m][1] = RD_A(4 + m, 1); }
    BAR(); LGKM0();
    __builtin_amdgcn_s_setprio(1);
#pragma unroll
    for (int m = 0; m < 4; ++m)
#pragma unroll
      for (int n = 0; n < 2; ++n) {
        acc[4 + m][n] = MFMA(a1[m][0], b0[n][0], acc[4 + m][n]);
        acc[4 + m][n] = MFMA(a1[m][1], b0[n][1], acc[4 + m][n]);
      }
    __builtin_amdgcn_s_setprio(0);
    BAR();
    // ---- phase 3: stage A0+A1(t+2) ----
#pragma unroll
    for (int n = 0; n < 2; ++n) { b1[n][0] = RD_B(2 + n, 0); b1[n][1] = RD_B(2 + n, 1); }
    if (t + 2 < NT2) { STAGE_A(0, t + 2); STAGE_A(1, t + 2); SCHED0(); }
    BAR(); LGKM0();
    __builtin_amdgcn_s_setprio(1);
#pragma unroll
    for (int m = 0; m < 4; ++m)
#pragma unroll
      for (int n = 0; n < 2; ++n) {
        acc[m][2 + n] = MFMA(a0[m][0], b1[n][0], acc[m][2 + n]);
        acc[m][2 + n] = MFMA(a0[m][1], b1[n][1], acc[m][2 + n]);
      }
    __builtin_amdgcn_s_setprio(0);
    BAR();
    // ---- phase 4 ----
    if (t + 2 < NT2) STAGE_B(0, t + 2);
    __builtin_amdgcn_s_setprio(1);
#pragma unroll
    for (int m = 0; m < 4; ++m)
#pragma unroll
      for (int n = 0; n < 2; ++n) {
        acc[4 + m][2 + n] = MFMA(a1[m][0], b1[n][0], acc[4 + m][2 + n]);
        acc[4 + m][2 + n] = MFMA(a1[m][1], b1[n][1], acc[4 + m][2 + n]);
      }
    __builtin_amdgcn_s_setprio(0);
    if (t + 2 < NT2) asm volatile("s_waitcnt vmcnt(6)" ::: "memory");
    else             asm volatile("s_waitcnt vmcnt(0)" ::: "memory");
    BAR();
  }

#pragma unroll
  for (int mh = 0; mh < 2; ++mh)
#pragma unroll
    for (int mf = 0; mf < 4; ++mf)
#pragma unroll
      for (int j = 0; j < 4; ++j) {
        const int slot = tm * 256 + wm * 128 + mh * 64 + mf * 16 + kq * 4 + j;
        if (slot < c) {
          const int tok = ltok[e * TTOK + slot];
          const float wt = lw[e * TTOK + slot];
          float* orow = out + (size_t)tok * HID + tn * 256;
#pragma unroll
          for (int n = 0; n < 4; ++n)
            atomicAdd(orow + wn * 64 + n * 16 + ln15, wt * acc[mh * 4 + mf][n][j]);
        }
      }
}

extern "C" void kernel_launch(void* const* d_in, const int* in_sizes, int n_in,
                              void* d_out, int out_size, void* d_ws, size_t ws_size,
                              hipStream_t stream) {
  const float* x  = (const float*)d_in[0];
  const float* gw = (const float*)d_in[1];
  const float* w1 = (const float*)d_in[2];
  const float* w3 = (const float*)d_in[3];
  const float* w2 = (const float*)d_in[4];
  float* out = (float*)d_out;

  char* ws = (char*)d_ws;
  size_t off = 0;
  auto take = [&](size_t bytes) -> char* {
    char* p = ws + off;
    off += (bytes + 255) & ~(size_t)255;
    return p;
  };
  bf16* xb    = (bf16*)take((size_t)TTOK * HID * 2);
  bf16* w1b   = (bf16*)take((size_t)NE * INTER * HID * 2);   // w3b MUST follow contiguously
  bf16* w3b   = (bf16*)take((size_t)NE * INTER * HID * 2);
  bf16* w2b   = (bf16*)take((size_t)NE * HID * INTER * 2);
  bf16* hbuf  = (bf16*)take((size_t)TTOK * 2 * INTER * 2);
  int*   topk_e = (int*)take(TTOK * 2 * 4);
  float* topk_w = (float*)take(TTOK * 2 * 4);
  int*   ltok   = (int*)take(NE * TTOK * 4);
  float* lwgt   = (float*)take(NE * TTOK * 4);
  int*   cntp   = (int*)take(64);
  int*   basep  = (int*)take(64);
  if (off > ws_size) return;

  hipMemsetAsync(d_out, 0, (size_t)out_size * 4, stream);

  cvt_f32_bf16<<<2048, 256, 0, stream>>>(x,  xb,  (long)TTOK * HID);
  cvt_f32_bf16<<<4096, 256, 0, stream>>>(w1, w1b, (long)NE * INTER * HID);
  cvt_f32_bf16<<<4096, 256, 0, stream>>>(w3, w3b, (long)NE * INTER * HID);
  cvt_f32_bf16<<<4096, 256, 0, stream>>>(w2, w2b, (long)NE * HID * INTER);

  router_kernel<<<TTOK / 4, 256, 0, stream>>>(x, gw, topk_e, topk_w);
  gather_sorted<<<NE, 256, 0, stream>>>(topk_e, topk_w, cntp, ltok, lwgt);
  prefix_kernel<<<1, 64, 0, stream>>>(cntp, basep);

  pass1_kernel<<<dim3(INTER / 128, TTOK / 256, NE), 512, 0, stream>>>(
      xb, w1b, hbuf, cntp, basep, ltok);
  pass2_kernel<<<dim3(HID / 256, TTOK / 256, NE), 512, 0, stream>>>(
      hbuf, w2b, out, cntp, basep, ltok, lwgt);
}

// Round 11
// 2103.370 us; speedup vs baseline: 1.1179x; 1.0992x over previous
//
#include <hip/hip_runtime.h>
#include <stdint.h>

#define NE    8
#define HID   2048
#define INTER 7168
#define TTOK  8192
#define NT1   (HID / 64)    // 32 K-tiles for pass1
#define NT2   (INTER / 64)  // 112 K-tiles for pass2

typedef __bf16 bf16;
typedef bf16 bf16x4 __attribute__((ext_vector_type(4)));
typedef bf16 bf16x8 __attribute__((ext_vector_type(8)));
typedef float f32x4 __attribute__((ext_vector_type(4)));

__device__ __forceinline__ void glds16(const void* g, void* l) {
  __builtin_amdgcn_global_load_lds((__attribute__((address_space(1))) void*)g,
                                   (__attribute__((address_space(3))) void*)l, 16, 0, 0);
}

// ---------------- fp32 -> bf16 conversion ----------------
__global__ void cvt_f32_bf16(const float* __restrict__ src, bf16* __restrict__ dst, long n) {
  long i = (long)blockIdx.x * blockDim.x + threadIdx.x;
  long stride = (long)gridDim.x * blockDim.x;
  for (long j = i * 4; j < n; j += stride * 4) {
    float4 v = *(const float4*)(src + j);
    bf16x4 o = {(bf16)v.x, (bf16)v.y, (bf16)v.z, (bf16)v.w};
    *(bf16x4*)(dst + j) = o;
  }
}

// ---------------- router ----------------
__global__ void router_kernel(const float* __restrict__ x, const float* __restrict__ gw,
                              int* __restrict__ topk_e, float* __restrict__ topk_w) {
  const int wid = threadIdx.x >> 6, lane = threadIdx.x & 63;
  const int t = blockIdx.x * 4 + wid;
  if (t >= TTOK) return;
  const float* xr = x + (size_t)t * HID;
  float xv[32];
#pragma unroll
  for (int i = 0; i < 32; ++i) xv[i] = xr[lane + 64 * i];
  float lg[NE];
#pragma unroll
  for (int e = 0; e < NE; ++e) {
    const float* g = gw + e * HID;
    float s = 0.f;
#pragma unroll
    for (int i = 0; i < 32; ++i) s += xv[i] * g[lane + 64 * i];
#pragma unroll
    for (int off = 32; off; off >>= 1) s += __shfl_down(s, off);
    lg[e] = s;
  }
  if (lane == 0) {
    int i1 = 0;
#pragma unroll
    for (int e = 1; e < NE; ++e) if (lg[e] > lg[i1]) i1 = e;
    int i2 = (i1 == 0) ? 1 : 0;
#pragma unroll
    for (int e = 0; e < NE; ++e) if (e != i2 && e != i1 && lg[e] > lg[i2]) i2 = e;
    float r = __expf(lg[i2] - lg[i1]);
    float wa = 1.f / (1.f + r);
    topk_e[2 * t] = i1; topk_e[2 * t + 1] = i2;
    topk_w[2 * t] = wa; topk_w[2 * t + 1] = 1.f - wa;
  }
}

// ---------------- stable sorted gather (wave-scan) + inverse map ----------------
// ltok[e*TTOK+k]: tokens routed to e, ascending. ppos[2t+j]: local position of
// (t, j-th chosen expert) within that expert's segment. cnt[e] written here.
__global__ void gather_sorted(const int* __restrict__ topk_e, const float* __restrict__ topk_w,
                              int* __restrict__ cnt, int* __restrict__ ltok,
                              float* __restrict__ lw, int* __restrict__ ppos) {
  const int e = blockIdx.x;      // 0..7
  const int tid = threadIdx.x;   // 0..255
  const int lane = tid & 63, wv = tid >> 6;
  __shared__ int wtot[4];
  __shared__ int basesh;
  if (tid == 0) basesh = 0;
  __syncthreads();
  for (int c0 = 0; c0 < TTOK; c0 += 256) {
    const int t = c0 + tid;
    const int e0 = topk_e[2 * t], e1 = topk_e[2 * t + 1];
    const int j = (e0 == e) ? 0 : 1;
    const int flag = (e0 == e) || (e1 == e);
    unsigned long long b = __ballot(flag);
    int wrank = __popcll(b & ((1ULL << lane) - 1ULL));
    if (lane == 63) wtot[wv] = __popcll(b);
    __syncthreads();
    int wbase = 0;
#pragma unroll
    for (int k = 0; k < 4; ++k) if (k < wv) wbase += wtot[k];
    const int total = wtot[0] + wtot[1] + wtot[2] + wtot[3];
    const int pos = basesh + wbase + wrank;
    if (flag) {
      ltok[e * TTOK + pos] = t;
      lw[e * TTOK + pos] = (j == 0) ? topk_w[2 * t] : topk_w[2 * t + 1];
      ppos[2 * t + j] = pos;
    }
    __syncthreads();
    if (tid == 0) basesh += total;
    __syncthreads();
  }
  if (tid == 0) cnt[e] = basesh;
}

__global__ void prefix_kernel(const int* __restrict__ cnt, int* __restrict__ base) {
  if (threadIdx.x == 0 && blockIdx.x == 0) {
    int b = 0;
    for (int e = 0; e < NE; ++e) { base[e] = b; b += cnt[e]; }
    base[NE] = b;   // = TTOK*2
  }
}

// ---------------- combine: out[t] = y[pair0(t)] + y[pair1(t)] ----------------
__global__ void combine_kernel(const float* __restrict__ ybuf, const int* __restrict__ topk_e,
                               const int* __restrict__ ppos, const int* __restrict__ basep,
                               float* __restrict__ out) {
  const int t = blockIdx.x;
  const int col = threadIdx.x * 8;
  const int g0 = basep[topk_e[2 * t]] + ppos[2 * t];
  const int g1 = basep[topk_e[2 * t + 1]] + ppos[2 * t + 1];
  const float4* y0 = (const float4*)(ybuf + (size_t)g0 * HID + col);
  const float4* y1 = (const float4*)(ybuf + (size_t)g1 * HID + col);
  float4* o = (float4*)(out + (size_t)t * HID + col);
  float4 a0 = y0[0], b0 = y1[0];
  float4 a1 = y0[1], b1 = y1[1];
  o[0] = make_float4(a0.x + b0.x, a0.y + b0.y, a0.z + b0.z, a0.w + b0.w);
  o[1] = make_float4(a1.x + b1.x, a1.y + b1.y, a1.z + b1.z, a1.w + b1.w);
}

// ============ 256x256 GEMM, 16x16x32 MFMA, read-pipelined counted-lgkm ============
// r6 barrier/stage/vmcnt skeleton unchanged (race audit identical). MFMA runs one
// slot BEHIND its ds_reads via counted lgkmcnt — each wait drains only reads issued
// one slot earlier (already complete), eliminating per-phase read-latency stalls:
//  s1: read a0(8)+b0(4); stage B1(t+1); BAR; lgkm(12); MFMA Q11(t-1); BAR
//  s2: read a1(8);                      BAR; lgkm(8);  MFMA Q00(t);   BAR
//  s3: read b1(4); stage A0+A1(t+2);    BAR; lgkm(4);  MFMA Q10(t);   BAR
//  s4: stage B0(t+2); lgkm(0) [drains b1, 1 slot old]; MFMA Q01(t); vmcnt(6); BAR
// Queue walk (in-order DS completion): entering s1 outstanding=0; s1-wait(12) keeps
// the 12 new; s2: 12+8 wait(8) drains a0b0; s3: 8+4 wait(4) drains a1; s4: wait(0)
// drains b1. Final Q11(NT-1) after loop (b1 already drained).

#define MFMA(a, b, c) __builtin_amdgcn_mfma_f32_16x16x32_bf16((a), (b), (c), 0, 0, 0)

#define STAGE_A(h, kt) do { int _b = ((kt) & 1) * 32768; size_t _k = (size_t)(kt) * 128; \
    glds16(bA + oA[(h)*2 + 0] + _k, ldsA + _b + (h) * 16384 + d0); \
    glds16(bA + oA[(h)*2 + 1] + _k, ldsA + _b + (h) * 16384 + d1); } while (0)
#define STAGE_B(h, kt) do { int _b = ((kt) & 1) * 32768; size_t _k = (size_t)(kt) * 128; \
    glds16(bB + oB[(h)*2 + 0] + _k, ldsB + _b + (h) * 16384 + d0); \
    glds16(bB + oB[(h)*2 + 1] + _k, ldsB + _b + (h) * 16384 + d1); } while (0)

#define RD_A(mf, ks) (*(const bf16x8*)(ldsA + curb + arow + (mf) * (16 * 128) + ((ks) ? kcol1 : kcol0)))
#define RD_B(nf, ks) (*(const bf16x8*)(ldsB + curb + brow + (nf) * (16 * 128) + ((ks) ? kcol1 : kcol0)))

#define BAR()    __builtin_amdgcn_s_barrier()
#define LGKMC(n) do { asm volatile("s_waitcnt lgkmcnt(" #n ")" ::: "memory"); \
                      __builtin_amdgcn_sched_barrier(0); } while (0)
#define SCHED0() __builtin_amdgcn_sched_barrier(0)

#define Q_MFMA(AM, BM, ACCM, ACCN_OFF) do { \
  __builtin_amdgcn_s_setprio(1); \
  _Pragma("unroll") \
  for (int m = 0; m < 4; ++m) \
    _Pragma("unroll") \
    for (int n = 0; n < 2; ++n) { \
      acc[ACCM + m][ACCN_OFF + n] = MFMA(AM[m][0], BM[n][0], acc[ACCM + m][ACCN_OFF + n]); \
      acc[ACCM + m][ACCN_OFF + n] = MFMA(AM[m][1], BM[n][1], acc[ACCM + m][ACCN_OFF + n]); \
    } \
  __builtin_amdgcn_s_setprio(0); \
} while (0)

// ---------------- pass1: h = silu(x w1^T) * (x w3^T) ----------------
__launch_bounds__(512, 2)
__global__ void pass1_kernel(const bf16* __restrict__ xb, const bf16* __restrict__ w1b,
                             bf16* __restrict__ hbuf, const int* __restrict__ cnt,
                             const int* __restrict__ basep, const int* __restrict__ ltok) {
  const int e = blockIdx.z;
  const int c = cnt[e];
  const int tm = blockIdx.y;
  if (tm * 256 >= c) return;
  const int tn = blockIdx.x;

  __shared__ __align__(16) bf16 sA[2][256 * 64];
  __shared__ __align__(16) bf16 sB[2][256 * 64];
  char* const ldsA = (char*)&sA[0][0];
  char* const ldsB = (char*)&sB[0][0];

  const int tid = threadIdx.x;
  const int r0 = tid >> 3;
  const int ls = (tid & 7) ^ (r0 & 7);
  const int d0 = tid * 16, d1 = (tid + 512) * 16;
  const char* const bA = (const char*)xb;
  const char* const bB = (const char*)w1b;  // w3b contiguous after w1b

  uint32_t oA[4], oB[4];
#pragma unroll
  for (int i = 0; i < 4; ++i) {
    int trow = i * 64 + r0;
    int slot = tm * 256 + trow; if (slot >= c) slot = c - 1;
    oA[i] = (uint32_t)((size_t)ltok[e * TTOK + slot] * (HID * 2) + ls * 16);
    int br = i * 64 + r0;
    int w = (br >> 4) & 1;
    int wr = tn * 128 + ((br >> 5) << 4) + (br & 15);
    size_t off = ((size_t)e * INTER + wr) * (HID * 2) + (size_t)ls * 16;
    if (w) off += (size_t)NE * INTER * HID * 2;
    oB[i] = (uint32_t)off;
  }

  const int lane = tid & 63, wid = tid >> 6;
  const int wm = wid >> 2, wn = wid & 3;
  const int ln15 = lane & 15, kq = lane >> 4;
  const int swz = (ln15 & 7) << 4;
  const int kcol0 = (kq * 16) ^ swz;
  const int kcol1 = (64 + kq * 16) ^ swz;
  const int arow = (wm * 128 + ln15) * 128;
  const int brow = (wn * 64 + ln15) * 128;

  f32x4 acc[8][4];
#pragma unroll
  for (int m = 0; m < 8; ++m)
#pragma unroll
    for (int n = 0; n < 4; ++n) acc[m][n] = (f32x4){0.f, 0.f, 0.f, 0.f};

  STAGE_A(0, 0); STAGE_A(1, 0); STAGE_B(0, 0); STAGE_B(1, 0);
  asm volatile("s_waitcnt vmcnt(4)" ::: "memory");
  STAGE_A(0, 1); STAGE_A(1, 1); STAGE_B(0, 1);
  asm volatile("s_waitcnt vmcnt(6)" ::: "memory");
  BAR();

  bf16x8 a0[4][2], a1[4][2], b0[2][2], b1[2][2];
  int cur = 0;
  for (int t = 0; t < NT1; ++t, cur ^= 1) {
    const int curb = cur * 32768;
    // ---- s1: read a0+b0(t); stage B1(t+1); MFMA Q11(t-1) ----
#pragma unroll
    for (int m = 0; m < 4; ++m) { a0[m][0] = RD_A(m, 0); a0[m][1] = RD_A(m, 1); }
#pragma unroll
    for (int n = 0; n < 2; ++n) { b0[n][0] = RD_B(n, 0); b0[n][1] = RD_B(n, 1); }
    if (t + 1 < NT1) STAGE_B(1, t + 1);
    BAR(); LGKMC(12);
    if (t > 0) Q_MFMA(a1, b1, 4, 2);
    BAR();
    // ---- s2: read a1(t); MFMA Q00(t) ----
#pragma unroll
    for (int m = 0; m < 4; ++m) { a1[m][0] = RD_A(4 + m, 0); a1[m][1] = RD_A(4 + m, 1); }
    BAR(); LGKMC(8);
    Q_MFMA(a0, b0, 0, 0);
    BAR();
    // ---- s3: read b1(t); stage A0+A1(t+2); MFMA Q10(t) ----
#pragma unroll
    for (int n = 0; n < 2; ++n) { b1[n][0] = RD_B(2 + n, 0); b1[n][1] = RD_B(2 + n, 1); }
    if (t + 2 < NT1) { STAGE_A(0, t + 2); STAGE_A(1, t + 2); SCHED0(); }
    BAR(); LGKMC(4);
    Q_MFMA(a1, b0, 4, 0);
    BAR();
    // ---- s4: stage B0(t+2); MFMA Q01(t); counted vmcnt ----
    if (t + 2 < NT1) STAGE_B(0, t + 2);
    LGKMC(0);
    Q_MFMA(a0, b1, 0, 2);
    if (t + 2 < NT1) asm volatile("s_waitcnt vmcnt(6)" ::: "memory");
    else             asm volatile("s_waitcnt vmcnt(0)" ::: "memory");
    BAR();
  }
  // deferred Q11 of the last tile (b1 drained at its s4 LGKMC(0))
  Q_MFMA(a1, b1, 4, 2);

  // epilogue: silu(g)*u, thread-local pairs (nf0,nf1) and (nf2,nf3)
  const int be = basep[e];
#pragma unroll
  for (int mh = 0; mh < 2; ++mh)
#pragma unroll
    for (int mf = 0; mf < 4; ++mf)
#pragma unroll
      for (int j = 0; j < 4; ++j) {
        const int slot = tm * 256 + wm * 128 + mh * 64 + mf * 16 + kq * 4 + j;
        if (slot < c) {
          bf16* hrow = hbuf + (size_t)(be + slot) * INTER + tn * 128;
#pragma unroll
          for (int p = 0; p < 2; ++p) {
            const float g = acc[mh * 4 + mf][2 * p][j];
            const float u = acc[mh * 4 + mf][2 * p + 1][j];
            const float hv = g / (1.f + __expf(-g)) * u;
            hrow[wn * 32 + p * 16 + ln15] = (bf16)hv;
          }
        }
      }
}

// ---------------- pass2: ybuf[pair,:] = w * (h w2^T), no atomics ----------------
__launch_bounds__(512, 2)
__global__ void pass2_kernel(const bf16* __restrict__ hbuf, const bf16* __restrict__ w2b,
                             float* __restrict__ ybuf, const int* __restrict__ cnt,
                             const int* __restrict__ basep, const float* __restrict__ lw) {
  const int e = blockIdx.z;
  const int c = cnt[e];
  const int tm = blockIdx.y;
  if (tm * 256 >= c) return;
  const int tn = blockIdx.x;

  __shared__ __align__(16) bf16 sA[2][256 * 64];
  __shared__ __align__(16) bf16 sB[2][256 * 64];
  char* const ldsA = (char*)&sA[0][0];
  char* const ldsB = (char*)&sB[0][0];

  const int tid = threadIdx.x;
  const int r0 = tid >> 3;
  const int ls = (tid & 7) ^ (r0 & 7);
  const int d0 = tid * 16, d1 = (tid + 512) * 16;
  const int be = basep[e];
  const char* const bA = (const char*)hbuf;
  const char* const bB = (const char*)w2b;

  uint32_t oA[4], oB[4];
#pragma unroll
  for (int i = 0; i < 4; ++i) {
    int trow = i * 64 + r0;
    int slot = tm * 256 + trow; if (slot >= c) slot = c - 1;
    oA[i] = (uint32_t)((size_t)(be + slot) * (INTER * 2) + ls * 16);
    oB[i] = (uint32_t)(((size_t)e * HID + tn * 256 + i * 64 + r0) * (INTER * 2) + (size_t)ls * 16);
  }

  const int lane = tid & 63, wid = tid >> 6;
  const int wm = wid >> 2, wn = wid & 3;
  const int ln15 = lane & 15, kq = lane >> 4;
  const int swz = (ln15 & 7) << 4;
  const int kcol0 = (kq * 16) ^ swz;
  const int kcol1 = (64 + kq * 16) ^ swz;
  const int arow = (wm * 128 + ln15) * 128;
  const int brow = (wn * 64 + ln15) * 128;

  f32x4 acc[8][4];
#pragma unroll
  for (int m = 0; m < 8; ++m)
#pragma unroll
    for (int n = 0; n < 4; ++n) acc[m][n] = (f32x4){0.f, 0.f, 0.f, 0.f};

  STAGE_A(0, 0); STAGE_A(1, 0); STAGE_B(0, 0); STAGE_B(1, 0);
  asm volatile("s_waitcnt vmcnt(4)" ::: "memory");
  STAGE_A(0, 1); STAGE_A(1, 1); STAGE_B(0, 1);
  asm volatile("s_waitcnt vmcnt(6)" ::: "memory");
  BAR();

  bf16x8 a0[4][2], a1[4][2], b0[2][2], b1[2][2];
  int cur = 0;
  for (int t = 0; t < NT2; ++t, cur ^= 1) {
    const int curb = cur * 32768;
    // ---- s1 ----
#pragma unroll
    for (int m = 0; m < 4; ++m) { a0[m][0] = RD_A(m, 0); a0[m][1] = RD_A(m, 1); }
#pragma unroll
    for (int n = 0; n < 2; ++n) { b0[n][0] = RD_B(n, 0); b0[n][1] = RD_B(n, 1); }
    if (t + 1 < NT2) STAGE_B(1, t + 1);
    BAR(); LGKMC(12);
    if (t > 0) Q_MFMA(a1, b1, 4, 2);
    BAR();
    // ---- s2 ----
#pragma unroll
    for (int m = 0; m < 4; ++m) { a1[m][0] = RD_A(4 + m, 0); a1[m][1] = RD_A(4 + m, 1); }
    BAR(); LGKMC(8);
    Q_MFMA(a0, b0, 0, 0);
    BAR();
    // ---- s3 ----
#pragma unroll
    for (int n = 0; n < 2; ++n) { b1[n][0] = RD_B(2 + n, 0); b1[n][1] = RD_B(2 + n, 1); }
    if (t + 2 < NT2) { STAGE_A(0, t + 2); STAGE_A(1, t + 2); SCHED0(); }
    BAR(); LGKMC(4);
    Q_MFMA(a1, b0, 4, 0);
    BAR();
    // ---- s4 ----
    if (t + 2 < NT2) STAGE_B(0, t + 2);
    LGKMC(0);
    Q_MFMA(a0, b1, 0, 2);
    if (t + 2 < NT2) asm volatile("s_waitcnt vmcnt(6)" ::: "memory");
    else             asm volatile("s_waitcnt vmcnt(0)" ::: "memory");
    BAR();
  }
  Q_MFMA(a1, b1, 4, 2);

#pragma unroll
  for (int mh = 0; mh < 2; ++mh)
#pragma unroll
    for (int mf = 0; mf < 4; ++mf)
#pragma unroll
      for (int j = 0; j < 4; ++j) {
        const int slot = tm * 256 + wm * 128 + mh * 64 + mf * 16 + kq * 4 + j;
        if (slot < c) {
          const float wt = lw[e * TTOK + slot];
          float* yrow = ybuf + (size_t)(be + slot) * HID + tn * 256;
#pragma unroll
          for (int n = 0; n < 4; ++n)
            yrow[wn * 64 + n * 16 + ln15] = wt * acc[mh * 4 + mf][n][j];
        }
      }
}

extern "C" void kernel_launch(void* const* d_in, const int* in_sizes, int n_in,
                              void* d_out, int out_size, void* d_ws, size_t ws_size,
                              hipStream_t stream) {
  const float* x  = (const float*)d_in[0];
  const float* gw = (const float*)d_in[1];
  const float* w1 = (const float*)d_in[2];
  const float* w3 = (const float*)d_in[3];
  const float* w2 = (const float*)d_in[4];
  float* out = (float*)d_out;

  char* ws = (char*)d_ws;
  size_t off = 0;
  auto take = [&](size_t bytes) -> char* {
    char* p = ws + off;
    off += (bytes + 255) & ~(size_t)255;
    return p;
  };
  bf16* xb    = (bf16*)take((size_t)TTOK * HID * 2);
  bf16* w1b   = (bf16*)take((size_t)NE * INTER * HID * 2);   // w3b MUST follow contiguously
  bf16* w3b   = (bf16*)take((size_t)NE * INTER * HID * 2);
  bf16* w2b   = (bf16*)take((size_t)NE * HID * INTER * 2);
  bf16* hbuf  = (bf16*)take((size_t)TTOK * 2 * INTER * 2);
  float* ybuf = (float*)take((size_t)TTOK * 2 * HID * 4);    // 134 MB
  int*   topk_e = (int*)take(TTOK * 2 * 4);
  float* topk_w = (float*)take(TTOK * 2 * 4);
  int*   ltok   = (int*)take(NE * TTOK * 4);
  float* lwgt   = (float*)take(NE * TTOK * 4);
  int*   ppos   = (int*)take(TTOK * 2 * 4);
  int*   cntp   = (int*)take(64);
  int*   basep  = (int*)take(64);
  if (off > ws_size) return;

  cvt_f32_bf16<<<2048, 256, 0, stream>>>(x,  xb,  (long)TTOK * HID);
  cvt_f32_bf16<<<4096, 256, 0, stream>>>(w1, w1b, (long)NE * INTER * HID);
  cvt_f32_bf16<<<4096, 256, 0, stream>>>(w3, w3b, (long)NE * INTER * HID);
  cvt_f32_bf16<<<4096, 256, 0, stream>>>(w2, w2b, (long)NE * HID * INTER);

  router_kernel<<<TTOK / 4, 256, 0, stream>>>(x, gw, topk_e, topk_w);
  gather_sorted<<<NE, 256, 0, stream>>>(topk_e, topk_w, cntp, ltok, lwgt, ppos);
  prefix_kernel<<<1, 64, 0, stream>>>(cntp, basep);

  pass1_kernel<<<dim3(INTER / 128, TTOK / 256, NE), 512, 0, stream>>>(
      xb, w1b, hbuf, cntp, basep, ltok);
  pass2_kernel<<<dim3(HID / 256, TTOK / 256, NE), 512, 0, stream>>>(
      hbuf, w2b, ybuf, cntp, basep, lwgt);
  combine_kernel<<<TTOK, 256, 0, stream>>>(ybuf, topk_e, ppos, basep, out);
}